// Round 4
// baseline (72.794 us; speedup 1.0000x reference)
//
#include <hip/hip_runtime.h>
#include <math.h>

// Dims (fixed by the problem)
#define NB     16
#define NCIN   384
#define NHD    24
#define NDIM   96            // HEADS*HD
#define NSTR   5
#define NDT    480           // NSTR*NDIM

// native vector type for nontemporal builtins (HIP float4 is a class -> rejected)
typedef float nfloat4 __attribute__((ext_vector_type(4)));

// ---------------------------------------------------------------------------
// Kernel 1: 8x8 average pool of x: (16,384,64,64) -> x8 (16*384, 64)
// one wave per (b,c) plane, lane = output pixel. x read once -> nt loads.
// ---------------------------------------------------------------------------
__global__ void __launch_bounds__(256) k_pool(const float* __restrict__ x,
                                              float* __restrict__ x8) {
    int plane = blockIdx.x * 4 + (threadIdx.x >> 6);   // b*384 + c
    int lane  = threadIdx.x & 63;
    int py = lane >> 3, px = lane & 7;
    const nfloat4* base = reinterpret_cast<const nfloat4*>(x) +
                          (size_t)plane * 1024 + py * 128 + px * 2;
    float acc = 0.f;
#pragma unroll
    for (int rr = 0; rr < 8; ++rr) {
        nfloat4 a = __builtin_nontemporal_load(base + rr * 16);
        nfloat4 b = __builtin_nontemporal_load(base + rr * 16 + 1);
        acc += a.x + a.y + a.z + a.w + b.x + b.y + b.z + b.w;
    }
    x8[plane * 64 + lane] = acc * (1.f / 64.f);
}

// ---------------------------------------------------------------------------
// Kernel 2: y8[row=b*64+pix][d] = sum_c x8[b][c][pix]*W1[c][d] + b1[d]
// grid (8 d-tiles, 32 pix-tiles) = 256 blocks, 256 threads.
// tile: 32 pix x 64 d, thread = 2 pix x 4 d. Register-staged double buffer:
// issue chunk k+1 global loads, compute chunk k, 1 barrier per chunk.
// ---------------------------------------------------------------------------
#define KC 64
__global__ void __launch_bounds__(256) k_proj(const float* __restrict__ x8,
                                              const float* __restrict__ W1,
                                              const float* __restrict__ b1,
                                              float* __restrict__ y8) {
    __shared__ float AL[2][KC][32];   // 16 KB
    __shared__ float BL[2][KC][64];   // 32 KB
    const int b    = blockIdx.y >> 1;
    const int pix0 = (blockIdx.y & 1) * 32;
    const int d0   = blockIdx.x * 64;
    const int tid  = threadIdx.x;
    const int pxg  = (tid & 15) * 2;     // pix pair
    const int dg   = (tid >> 4) * 4;     // 4 d's

    // per-thread staging indices
    const int ca0 = (tid) >> 3,        pga0 = (tid) & 7;
    const int ca1 = (tid + 256) >> 3,  pga1 = (tid + 256) & 7;
    int cb[4], jgb[4];
#pragma unroll
    for (int i = 0; i < 4; ++i) { int f = tid + i * 256; cb[i] = f >> 4; jgb[i] = f & 15; }

    float4 ra[2], rb[4];
    auto load_chunk = [&](int c0) {
        ra[0] = *reinterpret_cast<const float4*>(&x8[(b * 384 + c0 + ca0) * 64 + pix0 + pga0 * 4]);
        ra[1] = *reinterpret_cast<const float4*>(&x8[(b * 384 + c0 + ca1) * 64 + pix0 + pga1 * 4]);
#pragma unroll
        for (int i = 0; i < 4; ++i) {
            int d = d0 + jgb[i] * 4;
            rb[i] = (d < NDT) ? *reinterpret_cast<const float4*>(&W1[(c0 + cb[i]) * NDT + d])
                              : make_float4(0.f, 0.f, 0.f, 0.f);
        }
    };

    float acc[2][4] = {};
    load_chunk(0);
    int cur = 0;
    for (int k = 0; k < 6; ++k) {
        *reinterpret_cast<float4*>(&AL[cur][ca0][pga0 * 4]) = ra[0];
        *reinterpret_cast<float4*>(&AL[cur][ca1][pga1 * 4]) = ra[1];
#pragma unroll
        for (int i = 0; i < 4; ++i)
            *reinterpret_cast<float4*>(&BL[cur][cb[i]][jgb[i] * 4]) = rb[i];
        __syncthreads();
        if (k < 5) load_chunk((k + 1) * KC);   // overlap with compute below
#pragma unroll 8
        for (int c = 0; c < KC; ++c) {
            float2 a = *reinterpret_cast<const float2*>(&AL[cur][c][pxg]);
            float4 w = *reinterpret_cast<const float4*>(&BL[cur][c][dg]);
            acc[0][0] += a.x * w.x; acc[0][1] += a.x * w.y;
            acc[0][2] += a.x * w.z; acc[0][3] += a.x * w.w;
            acc[1][0] += a.y * w.x; acc[1][1] += a.y * w.y;
            acc[1][2] += a.y * w.z; acc[1][3] += a.y * w.w;
        }
        cur ^= 1;
    }
    if (d0 + dg < NDT) {
        float4 bv = *reinterpret_cast<const float4*>(&b1[d0 + dg]);
#pragma unroll
        for (int p = 0; p < 2; ++p) {
            int pix = pix0 + pxg + p;
            float4 v = make_float4(acc[p][0] + bv.x, acc[p][1] + bv.y,
                                   acc[p][2] + bv.z, acc[p][3] + bv.w);
            *reinterpret_cast<float4*>(&y8[(size_t)(b * 64 + pix) * NDT + d0 + dg]) = v;
        }
    }
}

// ---------------------------------------------------------------------------
// Kernel 3: per (B, head): clustering (hard + soft), cosine attention,
// out8[B][h*24+c][n].  grid 64 blocks (B*4+h), 256 threads (4 waves).
// ---------------------------------------------------------------------------
__global__ void __launch_bounds__(256) k_cluster(const float* __restrict__ y8,
                                                 const float* __restrict__ salpha,
                                                 const float* __restrict__ sbeta,
                                                 float* __restrict__ out8) {
    __shared__ float sl[5][64][25];     // [stream][pix][c] pitch 25 (bank spread)
    __shared__ float y2s[5][4][24];     // 2x2-pooled cluster centers per stream
    __shared__ float wb[2][64][5];      // assignment weights [module][token][m]
    __shared__ float aggL[8][25];       // agg sums; col 24 = count
    __shared__ float anL[8][24];        // normalized agg
    __shared__ float normL[8];

    const int bp = blockIdx.x;          // 0..63
    const int Bi = bp >> 2, h = bp & 3;
    const int tid = threadIdx.x;
    const int lane = tid & 63, wid = tid >> 6;

#pragma unroll
    for (int idx = tid; idx < 5 * 64 * 24; idx += 256) {
        int c = idx % 24;
        int pix = (idx / 24) & 63;
        int s = idx / (24 * 64);
        sl[s][pix][c] = y8[(size_t)(Bi * 64 + pix) * NDT + s * NDIM + h * NHD + c];
    }
    __syncthreads();
#pragma unroll
    for (int idx = tid; idx < 5 * 4 * 24; idx += 256) {
        int c = idx % 24;
        int m = (idx / 24) & 3;
        int s = idx / 96;
        int my = m >> 1, mx = m & 1;
        float acc = 0.f;
#pragma unroll
        for (int ry = 0; ry < 4; ++ry)
#pragma unroll
            for (int rx = 0; rx < 4; ++rx)
                acc += sl[s][(my * 4 + ry) * 8 + mx * 4 + rx][c];
        y2s[s][m][c] = acc * (1.f / 16.f);
    }
    __syncthreads();
    if (wid < 2) {
        const int i = wid, ks = 1 + 2 * i;
        float ka[24];
        float sumk2 = 0.f;
#pragma unroll
        for (int c = 0; c < 24; ++c) { ka[c] = sl[ks][lane][c]; sumk2 += ka[c] * ka[c]; }
        float sim[4];
#pragma unroll
        for (int m = 0; m < 4; ++m) {
            float kc2 = 0.f, dt = 0.f;
#pragma unroll
            for (int c = 0; c < 24; ++c) {
                float kv = y2s[ks][m][c];
                kc2 += kv * kv; dt += kv * ka[c];
            }
            sim[m] = 2.f * dt - kc2 - sumk2;    // = -d2
        }
        float w[4];
        if (i == 0) {
            int am = 0; float bv = sim[0];
#pragma unroll
            for (int m = 1; m < 4; ++m) if (sim[m] > bv) { bv = sim[m]; am = m; }
#pragma unroll
            for (int m = 0; m < 4; ++m) w[m] = (m == am) ? 1.f : 0.f;
        } else {
            float mx = fmaxf(fmaxf(sim[0], sim[1]), fmaxf(sim[2], sim[3]));
            float sum = 0.f;
#pragma unroll
            for (int m = 0; m < 4; ++m) { w[m] = expf(sim[m] - mx); sum += w[m]; }
            float inv = 1.f / sum;
#pragma unroll
            for (int m = 0; m < 4; ++m) w[m] *= inv;
        }
#pragma unroll
        for (int m = 0; m < 4; ++m) wb[i][lane][m] = w[m];
    }
    __syncthreads();
    if (tid < 200) {
        int i = tid / 100, rem = tid % 100;
        int m = rem / 25, c = rem % 25;
        int vs = 2 + 2 * i;
        float s = 0.f;
#pragma unroll 8
        for (int n = 0; n < 64; ++n) {
            float wv = wb[i][n][m];
            s += (c < 24) ? wv * sl[vs][n][c] : wv;
        }
        aggL[i * 4 + m][c] = s;
    }
    __syncthreads();
    if (tid < 192) {
        int mm = tid / 24, c = tid % 24;
        int i = mm >> 2, m = mm & 3;
        aggL[mm][c] = (y2s[2 + 2 * i][m][c] + aggL[mm][c]) / (1.f + aggL[mm][24]);
    }
    __syncthreads();
    if (tid < 8) {
        float s = 0.f;
#pragma unroll
        for (int c = 0; c < 24; ++c) s += aggL[tid][c] * aggL[tid][c];
        normL[tid] = sqrtf(s) + 1e-6f;
    }
    __syncthreads();
    if (tid < 192) {
        int mm = tid / 24, c = tid % 24;
        anL[mm][c] = aggL[mm][c] / normL[mm];
    }
    __syncthreads();
    {
        const int n = lane;
        float pa[24]; float p2 = 0.f;
#pragma unroll
        for (int c = 0; c < 24; ++c) { pa[c] = sl[0][n][c]; p2 += pa[c] * pa[c]; }
        float pinv = 1.f / (sqrtf(p2) + 1e-6f);
        float s2[8];
#pragma unroll
        for (int mm = 0; mm < 8; ++mm) {
            float dt = 0.f;
#pragma unroll
            for (int c = 0; c < 24; ++c) dt += anL[mm][c] * pa[c];
            s2[mm] = salpha[mm] * (dt * pinv) + sbeta[mm];
        }
        float mx = s2[0];
#pragma unroll
        for (int mm = 1; mm < 8; ++mm) mx = fmaxf(mx, s2[mm]);
        float sum = 0.f;
#pragma unroll
        for (int mm = 0; mm < 8; ++mm) { s2[mm] = expf(s2[mm] - mx); sum += s2[mm]; }
        float inv = 1.f / sum;
        const int c0 = wid * 6;
#pragma unroll
        for (int cc = 0; cc < 6; ++cc) {
            int c = c0 + cc;
            float v = 0.f;
#pragma unroll
            for (int mm = 0; mm < 8; ++mm) v += aggL[mm][c] * (s2[mm] * inv);
            out8[(size_t)(Bi * NDIM + h * NHD + c) * 64 + n] = v;
        }
    }
}

// ---------------------------------------------------------------------------
// Kernel 4 (fused proj2 + bilinear upsample + bias):
//   z[o][n] = sum_d out8[B][d][n] * W2[d][o]  (K=96, 12 o per block)
//   out[B][o][y][x] = bilerp(z[o], half-pixel, clamped) + b2[o]
// grid (32 o-tiles of 12, 16 B) = 512 blocks -> exactly 2 blocks/CU (balance).
// Store: 16 consecutive lanes write one contiguous 256B row-chunk, nt stores.
// ---------------------------------------------------------------------------
__global__ void __launch_bounds__(256) k_proj2up(const float* __restrict__ out8,
                                                 const float* __restrict__ W2,
                                                 const float* __restrict__ b2,
                                                 float* __restrict__ out) {
    __shared__ float AL[96][64];   // [d][n]   24 KB
    __shared__ float WL[96][12];   // [d][o]   4.5 KB
    __shared__ float ZT[12][65];   // [o][n]   3.1 KB (pad 65)
    const int Bi = blockIdx.y;
    const int o0 = blockIdx.x * 12;
    const int tid = threadIdx.x;

#pragma unroll
    for (int i = 0; i < 6; ++i) {          // AL: 1536 float4
        int f = tid + i * 256;
        int d = f >> 4, ng = f & 15;
        *reinterpret_cast<float4*>(&AL[d][ng * 4]) =
            *reinterpret_cast<const float4*>(&out8[(size_t)(Bi * NDIM + d) * 64 + ng * 4]);
    }
#pragma unroll
    for (int idx = tid; idx < 96 * 12; idx += 256) {   // WL: 1152 floats
        int d = idx / 12, o = idx - d * 12;
        WL[d][o] = W2[d * NCIN + o0 + o];
    }
    __syncthreads();
    // ---- proj2: thread (og = tid>>6, n = tid&63) computes 3 o's
    {
        const int n = tid & 63, og = tid >> 6;
        float a0 = 0.f, a1 = 0.f, a2 = 0.f;
#pragma unroll 8
        for (int d = 0; d < 96; ++d) {
            float a = AL[d][n];
            a0 += a * WL[d][og * 3 + 0];
            a1 += a * WL[d][og * 3 + 1];
            a2 += a * WL[d][og * 3 + 2];
        }
        ZT[og * 3 + 0][n] = a0;
        ZT[og * 3 + 1][n] = a1;
        ZT[og * 3 + 2][n] = a2;
    }
    __syncthreads();
    // ---- upsample: thread (ol = tid>>4 in 0..11, xq = tid&15)
    if (tid < 192) {
        const int ol = tid >> 4, xq = tid & 15;
        const float bias = b2[o0 + ol];

        float uxb = 0.125f * (float)(xq * 4) - 0.4375f;
        float uxbc = fminf(fmaxf(uxb, 0.f), 7.f);
        const int ixb = (int)uxbc;
        float wa[4], wbx[4], wc[4];
#pragma unroll
        for (int j = 0; j < 4; ++j) {
            float ux  = 0.125f * (float)(xq * 4 + j) - 0.4375f;
            float uxc = fminf(fmaxf(ux, 0.f), 7.f);
            int ix0 = (int)uxc;
            int ix1 = ix0 + 1 > 7 ? 7 : ix0 + 1;
            float fx = uxc - (float)ix0;
            int k0 = ix0 - ixb, k1 = ix1 - ixb;
            wa[j]  = ((k0 == 0) ? (1.f - fx) : 0.f) + ((k1 == 0) ? fx : 0.f);
            wbx[j] = ((k0 == 1) ? (1.f - fx) : 0.f) + ((k1 == 1) ? fx : 0.f);
            wc[j]  = ((k1 == 2) ? fx : 0.f);
        }
        float zc0[8], zc1[8], zc2[8];
        {
            const int i1 = ixb + 1 > 7 ? 7 : ixb + 1;
            const int i2 = ixb + 2 > 7 ? 7 : ixb + 2;
#pragma unroll
            for (int iy = 0; iy < 8; ++iy) {
                zc0[iy] = ZT[ol][iy * 8 + ixb];
                zc1[iy] = ZT[ol][iy * 8 + i1];
                zc2[iy] = ZT[ol][iy * 8 + i2];
            }
        }
        float* obase = out + (size_t)(Bi * NCIN + o0 + ol) * 4096 + xq * 4;
#pragma unroll
        for (int y = 0; y < 64; ++y) {      // full unroll: iy0/iy1/fy fold to consts
            const float u  = 0.125f * (float)y - 0.4375f;
            const float uc = fminf(fmaxf(u, 0.f), 7.f);
            const int iy0 = (int)uc;
            const int iy1 = iy0 + 1 > 7 ? 7 : iy0 + 1;
            const float fy = uc - (float)iy0;
            const float r0 = zc0[iy0] + fy * (zc0[iy1] - zc0[iy0]);
            const float r1 = zc1[iy0] + fy * (zc1[iy1] - zc1[iy0]);
            const float r2 = zc2[iy0] + fy * (zc2[iy1] - zc2[iy0]);
            nfloat4 v;
            v.x = bias + wa[0] * r0 + wbx[0] * r1 + wc[0] * r2;
            v.y = bias + wa[1] * r0 + wbx[1] * r1 + wc[1] * r2;
            v.z = bias + wa[2] * r0 + wbx[2] * r1 + wc[2] * r2;
            v.w = bias + wa[3] * r0 + wbx[3] * r1 + wc[3] * r2;
            __builtin_nontemporal_store(v, reinterpret_cast<nfloat4*>(obase + y * 64));
        }
    }
}

// ---------------------------------------------------------------------------
extern "C" void kernel_launch(void* const* d_in, const int* in_sizes, int n_in,
                              void* d_out, int out_size, void* d_ws, size_t ws_size,
                              hipStream_t stream) {
    const float* x  = (const float*)d_in[0];
    const float* W1 = (const float*)d_in[1];
    const float* b1 = (const float*)d_in[2];
    const float* W2 = (const float*)d_in[3];
    const float* b2 = (const float*)d_in[4];
    const float* sa = (const float*)d_in[5];
    const float* sb = (const float*)d_in[6];
    float* out = (float*)d_out;

    float* x8 = (float*)d_ws;                 // 16*384*64 = 393216 f
    float* y8 = x8 + 16 * 384 * 64;           // 1024*480  = 491520 f
    float* o8 = y8 + 1024 * 480;              // 16*96*64  =  98304 f

    k_pool<<<dim3(16 * 384 / 4), dim3(256), 0, stream>>>(x, x8);
    k_proj<<<dim3(8, 32), dim3(256), 0, stream>>>(x8, W1, b1, y8);
    k_cluster<<<dim3(64), dim3(256), 0, stream>>>(y8, sa, sb, o8);
    k_proj2up<<<dim3(32, 16), dim3(256), 0, stream>>>(o8, W2, b2, out);
}

// Round 5
// 68.298 us; speedup vs baseline: 1.0658x; 1.0658x over previous
//
#include <hip/hip_runtime.h>
#include <math.h>

// Dims (fixed by the problem)
#define NB     16
#define NCIN   384
#define NHD    24
#define NDIM   96            // HEADS*HD
#define NSTR   5
#define NDT    480           // NSTR*NDIM

// ---------------------------------------------------------------------------
// Kernel 1: 8x8 average pool of x: (16,384,64,64) -> x8 (16*384, 64)
// block = one (b,c) plane. Threads read CONSECUTIVE float4 -> each wave
// instruction is one contiguous 1KB segment (perfect HBM coalescing).
// 8x8 reduce via LDS partials.
// ---------------------------------------------------------------------------
__global__ void __launch_bounds__(256) k_pool(const float* __restrict__ x,
                                              float* __restrict__ x8) {
    __shared__ float part[64][17];     // [row][col-chunk] pad 17
    const int plane = blockIdx.x;      // b*384 + c
    const int t = threadIdx.x;
    const float4* xp = reinterpret_cast<const float4*>(x + (size_t)plane * 4096);
    const int chunk = t & 15;          // 4-float chunk within row
    const int rloc  = t >> 4;          // row within 16-row group
#pragma unroll
    for (int rr = 0; rr < 4; ++rr) {
        int row = rr * 16 + rloc;
        float4 v = xp[rr * 256 + t];   // consecutive across lanes
        part[row][chunk] = v.x + v.y + v.z + v.w;
    }
    __syncthreads();
    if (t < 64) {
        int py = t >> 3, px = t & 7;
        float s = 0.f;
#pragma unroll
        for (int r = 0; r < 8; ++r)
            s += part[py * 8 + r][px * 2] + part[py * 8 + r][px * 2 + 1];
        x8[(size_t)plane * 64 + t] = s * (1.f / 64.f);
    }
}

// ---------------------------------------------------------------------------
// Kernel 2: y8[row=b*64+pix][d] = sum_c x8[b][c][pix]*W1[c][d] + b1[d]
// grid (8 d-tiles, 32 pix-tiles) = 256 blocks, 256 threads.
// tile: 32 pix x 64 d, thread = 2 pix x 4 d.
// ---------------------------------------------------------------------------
#define KC 64
__global__ void __launch_bounds__(256) k_proj(const float* __restrict__ x8,
                                              const float* __restrict__ W1,
                                              const float* __restrict__ b1,
                                              float* __restrict__ y8) {
    __shared__ float AL[KC][32];   // [c][pix]  8 KB
    __shared__ float BL[KC][64];   // [c][d]   16 KB
    const int b    = blockIdx.y >> 1;
    const int pix0 = (blockIdx.y & 1) * 32;
    const int d0   = blockIdx.x * 64;
    const int tid  = threadIdx.x;
    const int pxg  = (tid & 15) * 2;     // pix pair
    const int dg   = (tid >> 4) * 4;     // 4 d's
    float acc[2][4] = {};
    for (int c0 = 0; c0 < 384; c0 += KC) {
        __syncthreads();
#pragma unroll
        for (int i = 0; i < 2; ++i) {    // AL: 512 float4
            int f = tid + i * 256;
            int c = f >> 3, pg = f & 7;
            *reinterpret_cast<float4*>(&AL[c][pg * 4]) =
                *reinterpret_cast<const float4*>(&x8[(b * 384 + c0 + c) * 64 + pix0 + pg * 4]);
        }
#pragma unroll
        for (int i = 0; i < 4; ++i) {    // BL: 1024 float4
            int f = tid + i * 256;
            int c = f >> 4, jg = f & 15;
            int d = d0 + jg * 4;
            float4 v = make_float4(0.f, 0.f, 0.f, 0.f);
            if (d < NDT) v = *reinterpret_cast<const float4*>(&W1[(c0 + c) * NDT + d]);
            *reinterpret_cast<float4*>(&BL[c][jg * 4]) = v;
        }
        __syncthreads();
#pragma unroll 8
        for (int c = 0; c < KC; ++c) {
            float2 a = *reinterpret_cast<const float2*>(&AL[c][pxg]);
            float4 w = *reinterpret_cast<const float4*>(&BL[c][dg]);
            acc[0][0] += a.x * w.x; acc[0][1] += a.x * w.y;
            acc[0][2] += a.x * w.z; acc[0][3] += a.x * w.w;
            acc[1][0] += a.y * w.x; acc[1][1] += a.y * w.y;
            acc[1][2] += a.y * w.z; acc[1][3] += a.y * w.w;
        }
    }
    if (d0 + dg < NDT) {
        float4 bv = *reinterpret_cast<const float4*>(&b1[d0 + dg]);
#pragma unroll
        for (int p = 0; p < 2; ++p) {
            int pix = pix0 + pxg + p;
            float4 v = make_float4(acc[p][0] + bv.x, acc[p][1] + bv.y,
                                   acc[p][2] + bv.z, acc[p][3] + bv.w);
            *reinterpret_cast<float4*>(&y8[(size_t)(b * 64 + pix) * NDT + d0 + dg]) = v;
        }
    }
}

// ---------------------------------------------------------------------------
// Kernel 3: per (B, head): clustering (hard + soft), cosine attention,
// out8[B][h*24+c][n].  grid 64 blocks (B*4+h), 256 threads (4 waves).
// ---------------------------------------------------------------------------
__global__ void __launch_bounds__(256) k_cluster(const float* __restrict__ y8,
                                                 const float* __restrict__ salpha,
                                                 const float* __restrict__ sbeta,
                                                 float* __restrict__ out8) {
    __shared__ float sl[5][64][25];     // [stream][pix][c] pitch 25 (bank spread)
    __shared__ float y2s[5][4][24];     // 2x2-pooled cluster centers per stream
    __shared__ float wb[2][64][5];      // assignment weights [module][token][m]
    __shared__ float aggL[8][25];       // agg sums; col 24 = count
    __shared__ float anL[8][24];        // normalized agg
    __shared__ float normL[8];

    const int bp = blockIdx.x;          // 0..63
    const int Bi = bp >> 2, h = bp & 3;
    const int tid = threadIdx.x;
    const int lane = tid & 63, wid = tid >> 6;

    // stage 5*64 rows of 24 floats as float4 (1920 vector loads total)
    for (int idx = tid; idx < 5 * 64 * 6; idx += 256) {
        int q = idx % 6;
        int row = idx / 6;              // s*64 + pix
        int pix = row & 63, s = row >> 6;
        float4 v = *reinterpret_cast<const float4*>(
            &y8[(size_t)(Bi * 64 + pix) * NDT + s * NDIM + h * NHD + q * 4]);
        int c = q * 4;
        sl[s][pix][c]     = v.x;
        sl[s][pix][c + 1] = v.y;
        sl[s][pix][c + 2] = v.z;
        sl[s][pix][c + 3] = v.w;
    }
    __syncthreads();
    for (int idx = tid; idx < 5 * 4 * 24; idx += 256) {
        int c = idx % 24;
        int m = (idx / 24) & 3;
        int s = idx / 96;
        int my = m >> 1, mx = m & 1;
        float acc = 0.f;
#pragma unroll
        for (int ry = 0; ry < 4; ++ry)
#pragma unroll
            for (int rx = 0; rx < 4; ++rx)
                acc += sl[s][(my * 4 + ry) * 8 + mx * 4 + rx][c];
        y2s[s][m][c] = acc * (1.f / 16.f);
    }
    __syncthreads();
    if (wid < 2) {
        const int i = wid, ks = 1 + 2 * i;
        float ka[24];
        float sumk2 = 0.f;
#pragma unroll
        for (int c = 0; c < 24; ++c) { ka[c] = sl[ks][lane][c]; sumk2 += ka[c] * ka[c]; }
        float sim[4];
#pragma unroll
        for (int m = 0; m < 4; ++m) {
            float kc2 = 0.f, dt = 0.f;
#pragma unroll
            for (int c = 0; c < 24; ++c) {
                float kv = y2s[ks][m][c];
                kc2 += kv * kv; dt += kv * ka[c];
            }
            sim[m] = 2.f * dt - kc2 - sumk2;    // = -d2
        }
        float w[4];
        if (i == 0) {
            int am = 0; float bv = sim[0];
#pragma unroll
            for (int m = 1; m < 4; ++m) if (sim[m] > bv) { bv = sim[m]; am = m; }
#pragma unroll
            for (int m = 0; m < 4; ++m) w[m] = (m == am) ? 1.f : 0.f;
        } else {
            float mx = fmaxf(fmaxf(sim[0], sim[1]), fmaxf(sim[2], sim[3]));
            float sum = 0.f;
#pragma unroll
            for (int m = 0; m < 4; ++m) { w[m] = expf(sim[m] - mx); sum += w[m]; }
            float inv = 1.f / sum;
#pragma unroll
            for (int m = 0; m < 4; ++m) w[m] *= inv;
        }
#pragma unroll
        for (int m = 0; m < 4; ++m) wb[i][lane][m] = w[m];
    }
    __syncthreads();
    if (tid < 200) {
        int i = tid / 100, rem = tid % 100;
        int m = rem / 25, c = rem % 25;
        int vs = 2 + 2 * i;
        float s = 0.f;
#pragma unroll 8
        for (int n = 0; n < 64; ++n) {
            float wv = wb[i][n][m];
            s += (c < 24) ? wv * sl[vs][n][c] : wv;
        }
        aggL[i * 4 + m][c] = s;
    }
    __syncthreads();
    if (tid < 192) {
        int mm = tid / 24, c = tid % 24;
        int i = mm >> 2, m = mm & 3;
        aggL[mm][c] = (y2s[2 + 2 * i][m][c] + aggL[mm][c]) / (1.f + aggL[mm][24]);
    }
    __syncthreads();
    if (tid < 8) {
        float s = 0.f;
#pragma unroll
        for (int c = 0; c < 24; ++c) s += aggL[tid][c] * aggL[tid][c];
        normL[tid] = sqrtf(s) + 1e-6f;
    }
    __syncthreads();
    if (tid < 192) {
        int mm = tid / 24, c = tid % 24;
        anL[mm][c] = aggL[mm][c] / normL[mm];
    }
    __syncthreads();
    {
        const int n = lane;
        float pa[24]; float p2 = 0.f;
#pragma unroll
        for (int c = 0; c < 24; ++c) { pa[c] = sl[0][n][c]; p2 += pa[c] * pa[c]; }
        float pinv = 1.f / (sqrtf(p2) + 1e-6f);
        float s2[8];
#pragma unroll
        for (int mm = 0; mm < 8; ++mm) {
            float dt = 0.f;
#pragma unroll
            for (int c = 0; c < 24; ++c) dt += anL[mm][c] * pa[c];
            s2[mm] = salpha[mm] * (dt * pinv) + sbeta[mm];
        }
        float mx = s2[0];
#pragma unroll
        for (int mm = 1; mm < 8; ++mm) mx = fmaxf(mx, s2[mm]);
        float sum = 0.f;
#pragma unroll
        for (int mm = 0; mm < 8; ++mm) { s2[mm] = expf(s2[mm] - mx); sum += s2[mm]; }
        float inv = 1.f / sum;
        const int c0 = wid * 6;
#pragma unroll
        for (int cc = 0; cc < 6; ++cc) {
            int c = c0 + cc;
            float v = 0.f;
#pragma unroll
            for (int mm = 0; mm < 8; ++mm) v += aggL[mm][c] * (s2[mm] * inv);
            out8[(size_t)(Bi * NDIM + h * NHD + c) * 64 + n] = v;
        }
    }
}

// ---------------------------------------------------------------------------
// Kernel 4 (fused proj2 + bilinear upsample + bias):
//   z[o][n] = sum_d out8[B][d][n] * W2[d][o]  (K=96, 24 o per block)
//   out[B][o][y][x] = bilerp(z[o], half-pixel, clamped) + b2[o]
// grid (16 o-tiles of 24, 16 B) = 256 blocks = exactly 1/CU (perfect balance:
// 393 KB of writes per CU). Store: 16 consecutive lanes write one contiguous
// 256B row-chunk.
// ---------------------------------------------------------------------------
__global__ void __launch_bounds__(256) k_proj2up(const float* __restrict__ out8,
                                                 const float* __restrict__ W2,
                                                 const float* __restrict__ b2,
                                                 float* __restrict__ out) {
    __shared__ float AL[96][64];   // [d][n]   24 KB
    __shared__ float WL[96][24];   // [d][o]    9 KB
    __shared__ float ZT[24][65];   // [o][n]  6.1 KB (pad 65)
    const int Bi = blockIdx.y;
    const int o0 = blockIdx.x * 24;
    const int tid = threadIdx.x;

#pragma unroll
    for (int i = 0; i < 6; ++i) {          // AL: 1536 float4
        int f = tid + i * 256;
        int d = f >> 4, ng = f & 15;
        *reinterpret_cast<float4*>(&AL[d][ng * 4]) =
            *reinterpret_cast<const float4*>(&out8[(size_t)(Bi * NDIM + d) * 64 + ng * 4]);
    }
    for (int idx = tid; idx < 96 * 6; idx += 256) {   // WL: 576 float4
        int d = idx / 6, q = idx % 6;
        *reinterpret_cast<float4*>(&WL[d][q * 4]) =
            *reinterpret_cast<const float4*>(&W2[d * NCIN + o0 + q * 4]);
    }
    __syncthreads();
    // ---- proj2: thread (og = tid>>6, n = tid&63) computes 6 o's (og*6..+5)
    {
        const int n = tid & 63, og = tid >> 6;
        float a0 = 0.f, a1 = 0.f, a2 = 0.f, a3 = 0.f, a4 = 0.f, a5 = 0.f;
#pragma unroll 8
        for (int d = 0; d < 96; ++d) {
            float a = AL[d][n];
            float2 w01 = *reinterpret_cast<const float2*>(&WL[d][og * 6 + 0]);
            float2 w23 = *reinterpret_cast<const float2*>(&WL[d][og * 6 + 2]);
            float2 w45 = *reinterpret_cast<const float2*>(&WL[d][og * 6 + 4]);
            a0 += a * w01.x; a1 += a * w01.y;
            a2 += a * w23.x; a3 += a * w23.y;
            a4 += a * w45.x; a5 += a * w45.y;
        }
        ZT[og * 6 + 0][n] = a0;
        ZT[og * 6 + 1][n] = a1;
        ZT[og * 6 + 2][n] = a2;
        ZT[og * 6 + 3][n] = a3;
        ZT[og * 6 + 4][n] = a4;
        ZT[og * 6 + 5][n] = a5;
    }
    __syncthreads();
    // ---- upsample: 384 (ol,xq) slots over 256 threads, 2 passes
#pragma unroll
    for (int pass = 0; pass < 2; ++pass) {
        int slot = pass * 256 + tid;
        if (slot < 24 * 16) {
            const int ol = slot >> 4, xq = slot & 15;
            const float bias = b2[o0 + ol];

            float uxb = 0.125f * (float)(xq * 4) - 0.4375f;
            float uxbc = fminf(fmaxf(uxb, 0.f), 7.f);
            const int ixb = (int)uxbc;
            float wa[4], wbx[4], wc[4];
#pragma unroll
            for (int j = 0; j < 4; ++j) {
                float ux  = 0.125f * (float)(xq * 4 + j) - 0.4375f;
                float uxc = fminf(fmaxf(ux, 0.f), 7.f);
                int ix0 = (int)uxc;
                int ix1 = ix0 + 1 > 7 ? 7 : ix0 + 1;
                float fx = uxc - (float)ix0;
                int k0 = ix0 - ixb, k1 = ix1 - ixb;
                wa[j]  = ((k0 == 0) ? (1.f - fx) : 0.f) + ((k1 == 0) ? fx : 0.f);
                wbx[j] = ((k0 == 1) ? (1.f - fx) : 0.f) + ((k1 == 1) ? fx : 0.f);
                wc[j]  = ((k1 == 2) ? fx : 0.f);
            }
            float zc0[8], zc1[8], zc2[8];
            {
                const int i1 = ixb + 1 > 7 ? 7 : ixb + 1;
                const int i2 = ixb + 2 > 7 ? 7 : ixb + 2;
#pragma unroll
                for (int iy = 0; iy < 8; ++iy) {
                    zc0[iy] = ZT[ol][iy * 8 + ixb];
                    zc1[iy] = ZT[ol][iy * 8 + i1];
                    zc2[iy] = ZT[ol][iy * 8 + i2];
                }
            }
            float* obase = out + (size_t)(Bi * NCIN + o0 + ol) * 4096 + xq * 4;
#pragma unroll
            for (int y = 0; y < 64; ++y) {  // full unroll: iy0/iy1/fy fold
                const float u  = 0.125f * (float)y - 0.4375f;
                const float uc = fminf(fmaxf(u, 0.f), 7.f);
                const int iy0 = (int)uc;
                const int iy1 = iy0 + 1 > 7 ? 7 : iy0 + 1;
                const float fy = uc - (float)iy0;
                const float r0 = zc0[iy0] + fy * (zc0[iy1] - zc0[iy0]);
                const float r1 = zc1[iy0] + fy * (zc1[iy1] - zc1[iy0]);
                const float r2 = zc2[iy0] + fy * (zc2[iy1] - zc2[iy0]);
                float4 v;
                v.x = bias + wa[0] * r0 + wbx[0] * r1 + wc[0] * r2;
                v.y = bias + wa[1] * r0 + wbx[1] * r1 + wc[1] * r2;
                v.z = bias + wa[2] * r0 + wbx[2] * r1 + wc[2] * r2;
                v.w = bias + wa[3] * r0 + wbx[3] * r1 + wc[3] * r2;
                *reinterpret_cast<float4*>(obase + y * 64) = v;
            }
        }
    }
}

// ---------------------------------------------------------------------------
extern "C" void kernel_launch(void* const* d_in, const int* in_sizes, int n_in,
                              void* d_out, int out_size, void* d_ws, size_t ws_size,
                              hipStream_t stream) {
    const float* x  = (const float*)d_in[0];
    const float* W1 = (const float*)d_in[1];
    const float* b1 = (const float*)d_in[2];
    const float* W2 = (const float*)d_in[3];
    const float* b2 = (const float*)d_in[4];
    const float* sa = (const float*)d_in[5];
    const float* sb = (const float*)d_in[6];
    float* out = (float*)d_out;

    float* x8 = (float*)d_ws;                 // 16*384*64 = 393216 f
    float* y8 = x8 + 16 * 384 * 64;           // 1024*480  = 491520 f
    float* o8 = y8 + 1024 * 480;              // 16*96*64  =  98304 f

    k_pool<<<dim3(16 * 384), dim3(256), 0, stream>>>(x, x8);
    k_proj<<<dim3(8, 32), dim3(256), 0, stream>>>(x8, W1, b1, y8);
    k_cluster<<<dim3(64), dim3(256), 0, stream>>>(y8, sa, sb, o8);
    k_proj2up<<<dim3(16, 16), dim3(256), 0, stream>>>(o8, W2, b2, out);
}